// Round 2
// baseline (4657.598 us; speedup 1.0000x reference)
//
#include <hip/hip_runtime.h>
#include <cstddef>
#include <cstdint>

typedef unsigned short u16;
typedef __attribute__((ext_vector_type(8))) unsigned short u16x8;
typedef __attribute__((ext_vector_type(8))) short s16x8;
typedef __attribute__((ext_vector_type(4))) float f32x4;

#define B_ 8
#define T_ 256
#define U_ 64
#define D_ 512
#define G_ 2048   // 4*DUNITS
#define OD 500

__device__ __forceinline__ float bf2f(u16 u){ unsigned v=((unsigned)u)<<16; return __builtin_bit_cast(float,v); }
__device__ __forceinline__ u16 f2bf(float f){ unsigned u=__builtin_bit_cast(unsigned,f); u += 0x7fffu + ((u>>16)&1u); return (u16)(u>>16); }
__device__ __forceinline__ float sigm(float x){ return 1.f/(1.f+expf(-x)); }
__device__ __forceinline__ float wredsum(float v){
  #pragma unroll
  for(int o=32;o;o>>=1) v += __shfl_xor(v,o);
  return v;
}
__device__ __forceinline__ float wredmax(float v){
  #pragma unroll
  for(int o=32;o;o>>=1) v = fmaxf(v,__shfl_xor(v,o));
  return v;
}

// ---------------- conversion kernels (one-time per call) ----------------
__global__ void k_f2bf(const float* __restrict__ s, u16* __restrict__ d, int n){
  int i=blockIdx.x*256+threadIdx.x; if(i<n) d[i]=f2bf(s[i]);
}
// d[c*R + r] = s[r*C + c]
__global__ void k_trans_bf(const float* __restrict__ s, u16* __restrict__ d, int R, int C){
  int i=blockIdx.x*256+threadIdx.x; if(i>=R*C) return;
  int c=i/R, r=i-c*R; d[i]=f2bf(s[(size_t)r*C+c]);
}
// att slice of W_ih0: d[g*512+e] = W_ih0[g*1024 + 512 + e]
__global__ void k_wi0a(const float* __restrict__ W, u16* __restrict__ d){
  int i=blockIdx.x*256+threadIdx.x; if(i>=G_*D_) return;
  int g=i>>9, e=i&511; d[i]=f2bf(W[(size_t)g*1024 + 512 + e]);
}
// WoT[o][j] = W_out[j][o], o padded to 512 with zeros
__global__ void k_woT(const float* __restrict__ W, u16* __restrict__ d){
  int i=blockIdx.x*256+threadIdx.x; if(i>=512*512) return;
  int o=i>>9, j=i&511; d[i] = (o<OD)? f2bf(W[(size_t)j*OD+o]) : (u16)0;
}

// ---------------- generic bf16-MFMA GEMM ----------------
// C[M,N] = act( A[M,K] @ B + bias1 + bias2 ), tiles 64x64, K%32==0, M%64==0, N%64==0.
// bT=0: B[k*ldb+n]; bT=1: B[n*ldb+k]. gidx: optional row gather for A.
__global__ __launch_bounds__(256) void k_gemm(
  const float* __restrict__ A, const int* __restrict__ gidx, int lda,
  const float* __restrict__ Bm, int ldb, int bT,
  const float* __restrict__ bias1, const float* __restrict__ bias2,
  int actTanh, int outBf16, void* __restrict__ C, int ldc, int K)
{
  __shared__ __align__(16) u16 As[64][40];
  __shared__ __align__(16) u16 Bs[64][40];
  int tid=threadIdx.x;
  int m0=blockIdx.x*64, n0=blockIdx.y*64;
  int w=tid>>6, l=tid&63;
  f32x4 acc[4];
  #pragma unroll
  for(int nt=0;nt<4;++nt) acc[nt]=(f32x4){0.f,0.f,0.f,0.f};
  int arow=tid>>2, aseg=tid&3;
  int ar = gidx ? gidx[m0+arow] : (m0+arow);
  const float* Ap = A + (size_t)ar*lda + aseg*8;

  for(int kt=0;kt<K/32;++kt){
    const float* ap = Ap + kt*32;
    f32x4 a0=*(const f32x4*)ap, a1=*(const f32x4*)(ap+4);
    #pragma unroll
    for(int i=0;i<4;++i){ As[arow][aseg*8+i]=f2bf(a0[i]); As[arow][aseg*8+4+i]=f2bf(a1[i]); }
    if(bT){
      const float* bp = Bm + (size_t)(n0+arow)*ldb + kt*32 + aseg*8;
      f32x4 b0=*(const f32x4*)bp, b1=*(const f32x4*)(bp+4);
      #pragma unroll
      for(int i=0;i<4;++i){ Bs[arow][aseg*8+i]=f2bf(b0[i]); Bs[arow][aseg*8+4+i]=f2bf(b1[i]); }
    } else {
      int bk=tid>>3, bn=(tid&7)*8;
      const float* bp = Bm + (size_t)(kt*32+bk)*ldb + n0 + bn;
      f32x4 b0=*(const f32x4*)bp, b1=*(const f32x4*)(bp+4);
      #pragma unroll
      for(int i=0;i<4;++i){ Bs[bn+i][bk]=f2bf(b0[i]); Bs[bn+4+i][bk]=f2bf(b1[i]); }
    }
    __syncthreads();
    s16x8 af = *(const s16x8*)&As[w*16 + (l&15)][(l>>4)*8];
    #pragma unroll
    for(int nt=0;nt<4;++nt){
      s16x8 bf = *(const s16x8*)&Bs[nt*16 + (l&15)][(l>>4)*8];
      acc[nt]=__builtin_amdgcn_mfma_f32_16x16x32_bf16(af,bf,acc[nt],0,0,0);
    }
    __syncthreads();
  }
  int mr = w*16 + ((l>>4)<<2), cc = l&15;
  #pragma unroll
  for(int nt=0;nt<4;++nt){
    int gn = n0 + nt*16 + cc;
    float bb = (bias1?bias1[gn]:0.f) + (bias2?bias2[gn]:0.f);
    #pragma unroll
    for(int r=0;r<4;++r){
      int gm = m0 + mr + r;
      float v = acc[nt][r] + bb;
      if(actTanh) v = tanhf(v);
      if(outBf16) ((u16*)C)[(size_t)gm*ldc+gn] = f2bf(v);
      else        ((float*)C)[(size_t)gm*ldc+gn] = v;
    }
  }
}

// ---------------- scan step kernels ----------------
// q[b][a] = tanh(b_att_dec[a] + sum_k h0[b][k] * W_att_dec[k][a]); WdT is [a][k] bf16
__global__ __launch_bounds__(128) void k_q(
  const float* __restrict__ h0prev, const u16* __restrict__ WdT,
  const float* __restrict__ b_att_dec, float* __restrict__ q_g)
{
  __shared__ float h0s[8*516];
  int tid=threadIdx.x;
  for(int i=tid;i<4096;i+=128) h0s[(i>>9)*516+(i&511)]=h0prev[i];
  __syncthreads();
  int a=blockIdx.x*16+(tid>>3), b=tid&7;
  const u16* wr=WdT+(size_t)a*512;
  float acc=0.f;
  for(int kc=0;kc<64;++kc){
    u16x8 v=*(const u16x8*)(wr+kc*8);
    #pragma unroll
    for(int i=0;i<8;++i) acc += bf2f(v[i])*h0s[b*516+kc*8+i];
  }
  q_g[b*512+a]=tanhf(acc+b_att_dec[a]);
}

// blocks 0..7: attention (e, softmax, att_c) for batch b at step u (skipped if u>=64)
// blocks 8..39: LSTM1 for step u-1 (skipped if u==0)
__global__ __launch_bounds__(256) void k_att(
  int u, const float* __restrict__ q_g, const u16* __restrict__ pe_bf,
  const u16* __restrict__ hs_bf, const int* __restrict__ hlens,
  float* __restrict__ attc,
  const float* __restrict__ h0prev, const float* __restrict__ h1prev,
  float* __restrict__ h1new, const u16* __restrict__ Wih1, const u16* __restrict__ Whh1,
  const float* __restrict__ b_ih1, const float* __restrict__ b_hh1,
  float* __restrict__ c1g, float* __restrict__ hdec)
{
  __shared__ float sm[2*8*516 + 512];
  int tid=threadIdx.x, bid=blockIdx.x;
  if(bid<8){
    if(u>=U_) return;
    int b=bid;
    float* qs=sm; float* ew=sm+512; float* red=sm+512+256;
    for(int i=tid;i<512;i+=256) qs[i]=q_g[b*512+i];
    __syncthreads();
    int wv=tid>>6, ln=tid&63, hl=hlens[b];
    for(int t=wv;t<256;t+=4){
      const u16* p = pe_bf + ((size_t)(b*256+t))*512 + ln*8;
      u16x8 v=*(const u16x8*)p;
      float a=0.f;
      #pragma unroll
      for(int i=0;i<8;++i) a += bf2f(v[i])*qs[ln*8+i];
      a=wredsum(a);
      if(ln==0) ew[t] = (t<hl)? a : -1e30f;
    }
    __syncthreads();
    float val=ew[tid];
    float m=wredmax(val);
    if(ln==0) red[wv]=m;
    __syncthreads();
    float M=fmaxf(fmaxf(red[0],red[1]),fmaxf(red[2],red[3]));
    float p=expf(val-M);
    float s=wredsum(p);
    if(ln==0) red[4+wv]=s;
    __syncthreads();
    float S=red[4]+red[5]+red[6]+red[7];
    ew[tid]=p/S;
    __syncthreads();
    for(int d=tid;d<512;d+=256){
      const u16* hp = hs_bf + (size_t)b*256*512 + d;
      float a=0.f;
      for(int t=0;t<256;++t) a += ew[t]*bf2f(hp[(size_t)t*512]);
      attc[b*512+d]=a;
    }
  } else {
    if(u==0) return;
    int j0=(bid-8)*16;
    float* xs=sm; float* hs=sm+8*516; float* gl=sm+2*8*516;
    for(int i=tid;i<4096;i+=256){ int b=i>>9,k=i&511; xs[b*516+k]=h0prev[i]; hs[b*516+k]=h1prev[i]; }
    __syncthreads();
    for(int task=tid;task<512;task+=256){
      int b=task&7, jj=(task>>3)&15, g=task>>7;
      int row=g*512+j0+jj;
      float a=b_ih1[row]+b_hh1[row];
      const u16* w1=Wih1+(size_t)row*512;
      const u16* w2=Whh1+(size_t)row*512;
      for(int kc=0;kc<64;++kc){
        u16x8 x1=*(const u16x8*)(w1+kc*8);
        u16x8 x2=*(const u16x8*)(w2+kc*8);
        #pragma unroll
        for(int i=0;i<8;++i) a += bf2f(x1[i])*xs[b*516+kc*8+i] + bf2f(x2[i])*hs[b*516+kc*8+i];
      }
      gl[(g*16+jj)*8+b]=a;
    }
    __syncthreads();
    if(tid<128){
      int b=tid&7, jj=tid>>3, j=j0+jj;
      float i_=sigm(gl[(0*16+jj)*8+b]), f_=sigm(gl[(1*16+jj)*8+b]);
      float g_=tanhf(gl[(2*16+jj)*8+b]), o_=sigm(gl[(3*16+jj)*8+b]);
      float c=f_*c1g[b*512+j]+i_*g_;
      float h=o_*tanhf(c);
      c1g[b*512+j]=c; h1new[b*512+j]=h;
      hdec[((size_t)(b*64+(u-1)))*512 + j]=h;
    }
  }
}

// LSTM0: gates = ey_pre + att_c @ Wi0a^T + h0 @ Whh0^T ; 32 blocks x 16 h-indices
__global__ __launch_bounds__(256) void k_lstm0(
  int u, const float* __restrict__ attc, const float* __restrict__ h0prev,
  float* __restrict__ h0new, float* __restrict__ c0g,
  const u16* __restrict__ Wi0a, const u16* __restrict__ Whh0,
  const float* __restrict__ ey_pre)
{
  __shared__ float sm[2*8*516 + 512];
  float* xs=sm; float* hs=sm+8*516; float* gl=sm+2*8*516;
  int tid=threadIdx.x, j0=blockIdx.x*16;
  for(int i=tid;i<4096;i+=256){ int b=i>>9,k=i&511; xs[b*516+k]=attc[i]; hs[b*516+k]=h0prev[i]; }
  __syncthreads();
  for(int task=tid;task<512;task+=256){
    int b=task&7, jj=(task>>3)&15, g=task>>7;
    int row=g*512+j0+jj;
    float a=ey_pre[((size_t)((b<<6)|u))*2048 + row];
    const u16* w1=Wi0a+(size_t)row*512;
    const u16* w2=Whh0+(size_t)row*512;
    for(int kc=0;kc<64;++kc){
      u16x8 x1=*(const u16x8*)(w1+kc*8);
      u16x8 x2=*(const u16x8*)(w2+kc*8);
      #pragma unroll
      for(int i=0;i<8;++i) a += bf2f(x1[i])*xs[b*516+kc*8+i] + bf2f(x2[i])*hs[b*516+kc*8+i];
    }
    gl[(g*16+jj)*8+b]=a;
  }
  __syncthreads();
  if(tid<128){
    int b=tid&7, jj=tid>>3, j=j0+jj;
    float i_=sigm(gl[(0*16+jj)*8+b]), f_=sigm(gl[(1*16+jj)*8+b]);
    float g_=tanhf(gl[(2*16+jj)*8+b]), o_=sigm(gl[(3*16+jj)*8+b]);
    float c=f_*c0g[b*512+j]+i_*g_;
    c0g[b*512+j]=c;
    h0new[b*512+j]=o_*tanhf(c);
  }
}

// ---------------- joint network ----------------
// out[b,t,u,o] = tanh(lin_enc[b,t,:]+lin_dec[b,u,:]) @ W_out + b_out
// block = (b, u, t-tile of 64). A staged in LDS (XOR-swizzled bf16), B-frags in regs from WoT.
__global__ __launch_bounds__(256) void k_joint(
  const float* __restrict__ lin_enc, const float* __restrict__ lin_dec,
  const u16* __restrict__ WoT, const float* __restrict__ b_out,
  float* __restrict__ out)
{
  __shared__ __align__(16) u16 As[64*512];
  __shared__ float ld_s[512];
  int tid=threadIdx.x, bid=blockIdx.x;
  int b=bid>>8, u=(bid>>2)&63, t0=(bid&3)*64;
  for(int i=tid;i<512;i+=256) ld_s[i]=lin_dec[((size_t)((b<<6)|u))*512 + i];
  __syncthreads();
  const float* le = lin_enc + ((size_t)(b*256 + t0))*512;
  for(int it=0;it<16;++it){
    int idx=it*256+tid;
    int row=idx>>6, c0=(idx&63)*8;
    f32x4 x0=*(const f32x4*)(le + (size_t)row*512 + c0);
    f32x4 x1=*(const f32x4*)(le + (size_t)row*512 + c0 + 4);
    u16x8 pk;
    #pragma unroll
    for(int i=0;i<4;++i){
      pk[i]  =f2bf(tanhf(x0[i]+ld_s[c0+i]));
      pk[4+i]=f2bf(tanhf(x1[i]+ld_s[c0+4+i]));
    }
    int sc = c0 ^ ((row&7)<<3);
    *(u16x8*)&As[row*512+sc]=pk;
  }
  __syncthreads();
  int w=tid>>6, l=tid&63;
  for(int ch=0;ch<8;++ch){
    int n0=ch*64 + w*16;
    int o = n0 + (l&15);
    s16x8 bfr[16];
    const u16* wp = WoT + (size_t)o*512 + ((l>>4)*8);
    #pragma unroll
    for(int ks=0;ks<16;++ks) bfr[ks]=*(const s16x8*)(wp + ks*32);
    float bo = (o<OD)? b_out[o] : 0.f;
    for(int mt=0;mt<4;++mt){
      f32x4 acc=(f32x4){0.f,0.f,0.f,0.f};
      int row = mt*16 + (l&15);
      int sw  = (row&7)<<3;
      #pragma unroll
      for(int ks=0;ks<16;++ks){
        int cidx=(ks*32 + (l>>4)*8) ^ sw;
        s16x8 af=*(const s16x8*)&As[row*512+cidx];
        acc=__builtin_amdgcn_mfma_f32_16x16x32_bf16(af,bfr[ks],acc,0,0,0);
      }
      if(o<OD){
        #pragma unroll
        for(int r=0;r<4;++r){
          int t = t0 + mt*16 + ((l>>4)<<2) + r;
          out[(((size_t)(b*256+t))*64 + u)*500 + o] = acc[r] + bo;
        }
      }
    }
  }
}

// ---------------- host launcher ----------------
extern "C" void kernel_launch(void* const* d_in, const int* in_sizes, int n_in,
                              void* d_out, int out_size, void* d_ws, size_t ws_size,
                              hipStream_t stream)
{
  (void)in_sizes; (void)n_in; (void)out_size; (void)ws_size;
  const float* hs_pad   =(const float*)d_in[0];
  const int*   ys       =(const int*)  d_in[1];
  const int*   hlens    =(const int*)  d_in[2];
  const float* emb      =(const float*)d_in[3];
  const float* W_ih0    =(const float*)d_in[4];
  const float* W_hh0    =(const float*)d_in[5];
  const float* b_ih0    =(const float*)d_in[6];
  const float* b_hh0    =(const float*)d_in[7];
  const float* W_ih1    =(const float*)d_in[8];
  const float* W_hh1    =(const float*)d_in[9];
  const float* b_ih1    =(const float*)d_in[10];
  const float* b_hh1    =(const float*)d_in[11];
  const float* W_att_enc=(const float*)d_in[12];
  const float* b_att_enc=(const float*)d_in[13];
  const float* W_att_dec=(const float*)d_in[14];
  const float* b_att_dec=(const float*)d_in[15];
  const float* W_lin_enc=(const float*)d_in[16];
  const float* b_lin_enc=(const float*)d_in[17];
  const float* W_lin_dec=(const float*)d_in[18];
  const float* W_out    =(const float*)d_in[19];
  const float* b_out    =(const float*)d_in[20];
  float* out=(float*)d_out;

  char* wp=(char*)d_ws;
  auto carve=[&](size_t bytes)->char*{ char* p=wp; wp += (bytes+255)&~(size_t)255; return p; };
  u16*   hs_bf  =(u16*)  carve((size_t)B_*T_*D_*2);
  u16*   pe_bf  =(u16*)  carve((size_t)B_*T_*D_*2);
  u16*   WdT    =(u16*)  carve((size_t)512*512*2);
  u16*   Wi0a   =(u16*)  carve((size_t)G_*512*2);
  u16*   Whh0b  =(u16*)  carve((size_t)G_*512*2);
  u16*   Wih1b  =(u16*)  carve((size_t)G_*512*2);
  u16*   Whh1b  =(u16*)  carve((size_t)G_*512*2);
  u16*   WoT    =(u16*)  carve((size_t)512*512*2);
  float* lin_enc=(float*)carve((size_t)B_*T_*512*4);
  float* ey_pre =(float*)carve((size_t)B_*U_*G_*4);
  float* hdec   =(float*)carve((size_t)B_*U_*512*4);
  float* lin_dec=(float*)carve((size_t)B_*U_*512*4);
  float* q_g    =(float*)carve(4096*4);
  float* attc   =(float*)carve(4096*4);
  float* states =(float*)carve(6*4096*4);
  float* h0buf=states; float* h1buf=states+2*4096;
  float* c0g=states+4*4096; float* c1g=states+5*4096;

  hipMemsetAsync(states,0,6*4096*4,stream);
  int n1=B_*T_*D_, n2=G_*512;
  k_f2bf    <<<(n1+255)/256,256,0,stream>>>(hs_pad,hs_bf,n1);
  k_trans_bf<<<(512*512+255)/256,256,0,stream>>>(W_att_dec,WdT,512,512);
  k_wi0a    <<<(n2+255)/256,256,0,stream>>>(W_ih0,Wi0a);
  k_f2bf    <<<(n2+255)/256,256,0,stream>>>(W_hh0,Whh0b,n2);
  k_f2bf    <<<(n2+255)/256,256,0,stream>>>(W_ih1,Wih1b,n2);
  k_f2bf    <<<(n2+255)/256,256,0,stream>>>(W_hh1,Whh1b,n2);
  k_woT     <<<(512*512+255)/256,256,0,stream>>>(W_out,WoT);

  // pre GEMMs
  k_gemm<<<dim3(32,8),256,0,stream>>>(hs_pad,nullptr,512, W_att_enc,512,0, b_att_enc,nullptr, 1,1, pe_bf,512, 512);
  k_gemm<<<dim3(32,8),256,0,stream>>>(hs_pad,nullptr,512, W_lin_enc,512,0, b_lin_enc,nullptr, 0,0, lin_enc,512, 512);
  k_gemm<<<dim3(8,32),256,0,stream>>>(emb,ys,512,        W_ih0,1024,1,    b_ih0,b_hh0,      0,0, ey_pre,2048, 512);

  // sequential scan: h0_{u-1} lives in h0buf[u&1]; h1_{v} lives in h1buf[(v+1)&1]
  for(int u=0;u<U_;++u){
    k_q    <<<32,128,0,stream>>>(h0buf+(u&1)*4096, WdT, b_att_dec, q_g);
    k_att  <<<40,256,0,stream>>>(u,q_g,pe_bf,hs_bf,hlens,attc,
              h0buf+(u&1)*4096, h1buf+((u+1)&1)*4096, h1buf+(u&1)*4096,
              Wih1b,Whh1b,b_ih1,b_hh1,c1g,hdec);
    k_lstm0<<<32,256,0,stream>>>(u,attc,h0buf+(u&1)*4096,h0buf+((u+1)&1)*4096,c0g,Wi0a,Whh0b,ey_pre);
  }
  // final LSTM1 for u-1 = 63
  k_att<<<40,256,0,stream>>>(64,q_g,pe_bf,hs_bf,hlens,attc,
          h0buf+0*4096, h1buf+1*4096, h1buf+0*4096,
          Wih1b,Whh1b,b_ih1,b_hh1,c1g,hdec);

  // post GEMM + joint
  k_gemm <<<dim3(8,8),256,0,stream>>>(hdec,nullptr,512, W_lin_dec,512,0, nullptr,nullptr, 0,0, lin_dec,512, 512);
  k_joint<<<2048,256,0,stream>>>(lin_enc,lin_dec,WoT,b_out,out);
}

// Round 3
// 4623.719 us; speedup vs baseline: 1.0073x; 1.0073x over previous
//
#include <hip/hip_runtime.h>
#include <cstddef>
#include <cstdint>

typedef unsigned short u16;
typedef __attribute__((ext_vector_type(8))) unsigned short u16x8;
typedef __attribute__((ext_vector_type(8))) short s16x8;
typedef __attribute__((ext_vector_type(4))) float f32x4;

#define B_ 8
#define T_ 256
#define U_ 64
#define D_ 512
#define G_ 2048   // 4*DUNITS
#define OD 500

__device__ __forceinline__ float bf2f(u16 u){ unsigned v=((unsigned)u)<<16; return __builtin_bit_cast(float,v); }
__device__ __forceinline__ u16 f2bf(float f){ unsigned u=__builtin_bit_cast(unsigned,f); u += 0x7fffu + ((u>>16)&1u); return (u16)(u>>16); }
__device__ __forceinline__ float sigm(float x){ return 1.f/(1.f+expf(-x)); }
__device__ __forceinline__ float wredsum(float v){
  #pragma unroll
  for(int o=32;o;o>>=1) v += __shfl_xor(v,o);
  return v;
}
__device__ __forceinline__ float wredmax(float v){
  #pragma unroll
  for(int o=32;o;o>>=1) v = fmaxf(v,__shfl_xor(v,o));
  return v;
}

// ---------------- conversion kernels (one-time per call) ----------------
__global__ void k_f2bf(const float* __restrict__ s, u16* __restrict__ d, int n){
  int i=blockIdx.x*256+threadIdx.x; if(i<n) d[i]=f2bf(s[i]);
}
// d[c*R + r] = s[r*C + c]
__global__ void k_trans_bf(const float* __restrict__ s, u16* __restrict__ d, int R, int C){
  int i=blockIdx.x*256+threadIdx.x; if(i>=R*C) return;
  int c=i/R, r=i-c*R; d[i]=f2bf(s[(size_t)r*C+c]);
}
// att slice of W_ih0: d[g*512+e] = W_ih0[g*1024 + 512 + e]
__global__ void k_wi0a(const float* __restrict__ W, u16* __restrict__ d){
  int i=blockIdx.x*256+threadIdx.x; if(i>=G_*D_) return;
  int g=i>>9, e=i&511; d[i]=f2bf(W[(size_t)g*1024 + 512 + e]);
}
// WoT[o][j] = W_out[j][o], o padded to 512 with zeros
__global__ void k_woT(const float* __restrict__ W, u16* __restrict__ d){
  int i=blockIdx.x*256+threadIdx.x; if(i>=512*512) return;
  int o=i>>9, j=i&511; d[i] = (o<OD)? f2bf(W[(size_t)j*OD+o]) : (u16)0;
}

// ---------------- generic bf16-MFMA GEMM ----------------
// C[M,N] = act( A[M,K] @ B + bias1 + bias2 ), tiles 64x64, K%32==0, M%64==0, N%64==0.
// bT=0: B[k*ldb+n]; bT=1: B[n*ldb+k]. gidx: optional row gather for A.
__global__ __launch_bounds__(256) void k_gemm(
  const float* __restrict__ A, const int* __restrict__ gidx, int lda,
  const float* __restrict__ Bm, int ldb, int bT,
  const float* __restrict__ bias1, const float* __restrict__ bias2,
  int actTanh, int outBf16, void* __restrict__ C, int ldc, int K)
{
  __shared__ __align__(16) u16 As[64][40];
  __shared__ __align__(16) u16 Bs[64][40];
  int tid=threadIdx.x;
  int m0=blockIdx.x*64, n0=blockIdx.y*64;
  int w=tid>>6, l=tid&63;
  f32x4 acc[4];
  #pragma unroll
  for(int nt=0;nt<4;++nt) acc[nt]=(f32x4){0.f,0.f,0.f,0.f};
  int arow=tid>>2, aseg=tid&3;
  int ar = gidx ? gidx[m0+arow] : (m0+arow);
  const float* Ap = A + (size_t)ar*lda + aseg*8;

  for(int kt=0;kt<K/32;++kt){
    const float* ap = Ap + kt*32;
    f32x4 a0=*(const f32x4*)ap, a1=*(const f32x4*)(ap+4);
    #pragma unroll
    for(int i=0;i<4;++i){ As[arow][aseg*8+i]=f2bf(a0[i]); As[arow][aseg*8+4+i]=f2bf(a1[i]); }
    if(bT){
      const float* bp = Bm + (size_t)(n0+arow)*ldb + kt*32 + aseg*8;
      f32x4 b0=*(const f32x4*)bp, b1=*(const f32x4*)(bp+4);
      #pragma unroll
      for(int i=0;i<4;++i){ Bs[arow][aseg*8+i]=f2bf(b0[i]); Bs[arow][aseg*8+4+i]=f2bf(b1[i]); }
    } else {
      int bk=tid>>3, bn=(tid&7)*8;
      const float* bp = Bm + (size_t)(kt*32+bk)*ldb + n0 + bn;
      f32x4 b0=*(const f32x4*)bp, b1=*(const f32x4*)(bp+4);
      #pragma unroll
      for(int i=0;i<4;++i){ Bs[bn+i][bk]=f2bf(b0[i]); Bs[bn+4+i][bk]=f2bf(b1[i]); }
    }
    __syncthreads();
    s16x8 af = *(const s16x8*)&As[w*16 + (l&15)][(l>>4)*8];
    #pragma unroll
    for(int nt=0;nt<4;++nt){
      s16x8 bf = *(const s16x8*)&Bs[nt*16 + (l&15)][(l>>4)*8];
      acc[nt]=__builtin_amdgcn_mfma_f32_16x16x32_bf16(af,bf,acc[nt],0,0,0);
    }
    __syncthreads();
  }
  int mr = w*16 + ((l>>4)<<2), cc = l&15;
  #pragma unroll
  for(int nt=0;nt<4;++nt){
    int gn = n0 + nt*16 + cc;
    float bb = (bias1?bias1[gn]:0.f) + (bias2?bias2[gn]:0.f);
    #pragma unroll
    for(int r=0;r<4;++r){
      int gm = m0 + mr + r;
      float v = acc[nt][r] + bb;
      if(actTanh) v = tanhf(v);
      if(outBf16) ((u16*)C)[(size_t)gm*ldc+gn] = f2bf(v);
      else        ((float*)C)[(size_t)gm*ldc+gn] = v;
    }
  }
}

// ---------------- scan step kernels ----------------
// q[b][a] = tanh(b_att_dec[a] + sum_k h0[b][k] * W_att_dec[k][a]); WdT is [a][k] bf16
__global__ __launch_bounds__(128) void k_q(
  const float* __restrict__ h0prev, const u16* __restrict__ WdT,
  const float* __restrict__ b_att_dec, float* __restrict__ q_g)
{
  __shared__ float h0s[8*516];
  int tid=threadIdx.x;
  for(int i=tid;i<4096;i+=128) h0s[(i>>9)*516+(i&511)]=h0prev[i];
  __syncthreads();
  int a=blockIdx.x*16+(tid>>3), b=tid&7;
  const u16* wr=WdT+(size_t)a*512;
  float acc=0.f;
  for(int kc=0;kc<64;++kc){
    u16x8 v=*(const u16x8*)(wr+kc*8);
    #pragma unroll
    for(int i=0;i<8;++i) acc += bf2f(v[i])*h0s[b*516+kc*8+i];
  }
  q_g[b*512+a]=tanhf(acc+b_att_dec[a]);
}

// blocks 0..7: attention (e, softmax, att_c) for batch b at step u (skipped if u>=64)
// blocks 8..39: LSTM1 for step u-1 (skipped if u==0)
__global__ __launch_bounds__(256) void k_att(
  int u, const float* __restrict__ q_g, const u16* __restrict__ pe_bf,
  const u16* __restrict__ hs_bf, const int* __restrict__ hlens,
  float* __restrict__ attc,
  const float* __restrict__ h0prev, const float* __restrict__ h1prev,
  float* __restrict__ h1new, const u16* __restrict__ Wih1, const u16* __restrict__ Whh1,
  const float* __restrict__ b_ih1, const float* __restrict__ b_hh1,
  float* __restrict__ c1g, float* __restrict__ hdec)
{
  __shared__ float sm[2*8*516 + 512];
  int tid=threadIdx.x, bid=blockIdx.x;
  if(bid<8){
    if(u>=U_) return;
    int b=bid;
    float* qs=sm; float* ew=sm+512; float* red=sm+512+256;
    for(int i=tid;i<512;i+=256) qs[i]=q_g[b*512+i];
    __syncthreads();
    int wv=tid>>6, ln=tid&63, hl=hlens[b];
    for(int t=wv;t<256;t+=4){
      const u16* p = pe_bf + ((size_t)(b*256+t))*512 + ln*8;
      u16x8 v=*(const u16x8*)p;
      float a=0.f;
      #pragma unroll
      for(int i=0;i<8;++i) a += bf2f(v[i])*qs[ln*8+i];
      a=wredsum(a);
      if(ln==0) ew[t] = (t<hl)? a : -1e30f;
    }
    __syncthreads();
    float val=ew[tid];
    float m=wredmax(val);
    if(ln==0) red[wv]=m;
    __syncthreads();
    float M=fmaxf(fmaxf(red[0],red[1]),fmaxf(red[2],red[3]));
    float p=expf(val-M);
    float s=wredsum(p);
    if(ln==0) red[4+wv]=s;
    __syncthreads();
    float S=red[4]+red[5]+red[6]+red[7];
    ew[tid]=p/S;
    __syncthreads();
    for(int d=tid;d<512;d+=256){
      const u16* hp = hs_bf + (size_t)b*256*512 + d;
      float a=0.f;
      for(int t=0;t<256;++t) a += ew[t]*bf2f(hp[(size_t)t*512]);
      attc[b*512+d]=a;
    }
  } else {
    if(u==0) return;
    int j0=(bid-8)*16;
    float* xs=sm; float* hs=sm+8*516; float* gl=sm+2*8*516;
    for(int i=tid;i<4096;i+=256){ int b=i>>9,k=i&511; xs[b*516+k]=h0prev[i]; hs[b*516+k]=h1prev[i]; }
    __syncthreads();
    for(int task=tid;task<512;task+=256){
      int b=task&7, jj=(task>>3)&15, g=task>>7;
      int row=g*512+j0+jj;
      float a=b_ih1[row]+b_hh1[row];
      const u16* w1=Wih1+(size_t)row*512;
      const u16* w2=Whh1+(size_t)row*512;
      for(int kc=0;kc<64;++kc){
        u16x8 x1=*(const u16x8*)(w1+kc*8);
        u16x8 x2=*(const u16x8*)(w2+kc*8);
        #pragma unroll
        for(int i=0;i<8;++i) a += bf2f(x1[i])*xs[b*516+kc*8+i] + bf2f(x2[i])*hs[b*516+kc*8+i];
      }
      gl[(g*16+jj)*8+b]=a;
    }
    __syncthreads();
    if(tid<128){
      int b=tid&7, jj=tid>>3, j=j0+jj;
      float i_=sigm(gl[(0*16+jj)*8+b]), f_=sigm(gl[(1*16+jj)*8+b]);
      float g_=tanhf(gl[(2*16+jj)*8+b]), o_=sigm(gl[(3*16+jj)*8+b]);
      float c=f_*c1g[b*512+j]+i_*g_;
      float h=o_*tanhf(c);
      c1g[b*512+j]=c; h1new[b*512+j]=h;
      hdec[((size_t)(b*64+(u-1)))*512 + j]=h;
    }
  }
}

// LSTM0: gates = ey_pre + att_c @ Wi0a^T + h0 @ Whh0^T ; 32 blocks x 16 h-indices
__global__ __launch_bounds__(256) void k_lstm0(
  int u, const float* __restrict__ attc, const float* __restrict__ h0prev,
  float* __restrict__ h0new, float* __restrict__ c0g,
  const u16* __restrict__ Wi0a, const u16* __restrict__ Whh0,
  const float* __restrict__ ey_pre)
{
  __shared__ float sm[2*8*516 + 512];
  float* xs=sm; float* hs=sm+8*516; float* gl=sm+2*8*516;
  int tid=threadIdx.x, j0=blockIdx.x*16;
  for(int i=tid;i<4096;i+=256){ int b=i>>9,k=i&511; xs[b*516+k]=attc[i]; hs[b*516+k]=h0prev[i]; }
  __syncthreads();
  for(int task=tid;task<512;task+=256){
    int b=task&7, jj=(task>>3)&15, g=task>>7;
    int row=g*512+j0+jj;
    float a=ey_pre[((size_t)((b<<6)|u))*2048 + row];
    const u16* w1=Wi0a+(size_t)row*512;
    const u16* w2=Whh0+(size_t)row*512;
    for(int kc=0;kc<64;++kc){
      u16x8 x1=*(const u16x8*)(w1+kc*8);
      u16x8 x2=*(const u16x8*)(w2+kc*8);
      #pragma unroll
      for(int i=0;i<8;++i) a += bf2f(x1[i])*xs[b*516+kc*8+i] + bf2f(x2[i])*hs[b*516+kc*8+i];
    }
    gl[(g*16+jj)*8+b]=a;
  }
  __syncthreads();
  if(tid<128){
    int b=tid&7, jj=tid>>3, j=j0+jj;
    float i_=sigm(gl[(0*16+jj)*8+b]), f_=sigm(gl[(1*16+jj)*8+b]);
    float g_=tanhf(gl[(2*16+jj)*8+b]), o_=sigm(gl[(3*16+jj)*8+b]);
    float c=f_*c0g[b*512+j]+i_*g_;
    c0g[b*512+j]=c;
    h0new[b*512+j]=o_*tanhf(c);
  }
}

// ---------------- joint network ----------------
// out[b,t,u,o] = tanh(lin_enc[b,t,:]+lin_dec[b,u,:]) @ W_out + b_out
// block = (b, u, t-tile of 64). A staged in LDS (XOR-swizzled bf16), B-frags in regs from WoT.
__global__ __launch_bounds__(256) void k_joint(
  const float* __restrict__ lin_enc, const float* __restrict__ lin_dec,
  const u16* __restrict__ WoT, const float* __restrict__ b_out,
  float* __restrict__ out)
{
  __shared__ __align__(16) u16 As[64*512];
  __shared__ float ld_s[512];
  int tid=threadIdx.x, bid=blockIdx.x;
  int b=bid>>8, u=(bid>>2)&63, t0=(bid&3)*64;
  for(int i=tid;i<512;i+=256) ld_s[i]=lin_dec[((size_t)((b<<6)|u))*512 + i];
  __syncthreads();
  const float* le = lin_enc + ((size_t)(b*256 + t0))*512;
  for(int it=0;it<16;++it){
    int idx=it*256+tid;
    int row=idx>>6, c0=(idx&63)*8;
    f32x4 x0=*(const f32x4*)(le + (size_t)row*512 + c0);
    f32x4 x1=*(const f32x4*)(le + (size_t)row*512 + c0 + 4);
    u16x8 pk;
    #pragma unroll
    for(int i=0;i<4;++i){
      pk[i]  =f2bf(tanhf(x0[i]+ld_s[c0+i]));
      pk[4+i]=f2bf(tanhf(x1[i]+ld_s[c0+4+i]));
    }
    int sc = c0 ^ ((row&7)<<3);
    *(u16x8*)&As[row*512+sc]=pk;
  }
  __syncthreads();
  int w=tid>>6, l=tid&63;
  for(int ch=0;ch<8;++ch){
    int n0=ch*64 + w*16;
    int o = n0 + (l&15);
    s16x8 bfr[16];
    const u16* wp = WoT + (size_t)o*512 + ((l>>4)*8);
    #pragma unroll
    for(int ks=0;ks<16;++ks) bfr[ks]=*(const s16x8*)(wp + ks*32);
    float bo = (o<OD)? b_out[o] : 0.f;
    for(int mt=0;mt<4;++mt){
      f32x4 acc=(f32x4){0.f,0.f,0.f,0.f};
      int row = mt*16 + (l&15);
      int sw  = (row&7)<<3;
      #pragma unroll
      for(int ks=0;ks<16;++ks){
        int cidx=(ks*32 + (l>>4)*8) ^ sw;
        s16x8 af=*(const s16x8*)&As[row*512+cidx];
        acc=__builtin_amdgcn_mfma_f32_16x16x32_bf16(af,bfr[ks],acc,0,0,0);
      }
      if(o<OD){
        #pragma unroll
        for(int r=0;r<4;++r){
          int t = t0 + mt*16 + ((l>>4)<<2) + r;
          out[(((size_t)(b*256+t))*64 + u)*500 + o] = acc[r] + bo;
        }
      }
    }
  }
}

// ---------------- host launcher ----------------
extern "C" void kernel_launch(void* const* d_in, const int* in_sizes, int n_in,
                              void* d_out, int out_size, void* d_ws, size_t ws_size,
                              hipStream_t stream)
{
  (void)in_sizes; (void)n_in; (void)out_size; (void)ws_size;
  const float* hs_pad   =(const float*)d_in[0];
  const int*   ys       =(const int*)  d_in[1];
  const int*   hlens    =(const int*)  d_in[2];
  const float* emb      =(const float*)d_in[3];
  const float* W_ih0    =(const float*)d_in[4];
  const float* W_hh0    =(const float*)d_in[5];
  const float* b_ih0    =(const float*)d_in[6];
  const float* b_hh0    =(const float*)d_in[7];
  const float* W_ih1    =(const float*)d_in[8];
  const float* W_hh1    =(const float*)d_in[9];
  const float* b_ih1    =(const float*)d_in[10];
  const float* b_hh1    =(const float*)d_in[11];
  const float* W_att_enc=(const float*)d_in[12];
  const float* b_att_enc=(const float*)d_in[13];
  const float* W_att_dec=(const float*)d_in[14];
  const float* b_att_dec=(const float*)d_in[15];
  const float* W_lin_enc=(const float*)d_in[16];
  const float* b_lin_enc=(const float*)d_in[17];
  const float* W_lin_dec=(const float*)d_in[18];
  const float* W_out    =(const float*)d_in[19];
  const float* b_out    =(const float*)d_in[20];
  float* out=(float*)d_out;

  char* wp=(char*)d_ws;
  auto carve=[&](size_t bytes)->char*{ char* p=wp; wp += (bytes+255)&~(size_t)255; return p; };
  u16*   hs_bf  =(u16*)  carve((size_t)B_*T_*D_*2);
  u16*   pe_bf  =(u16*)  carve((size_t)B_*T_*D_*2);
  u16*   WdT    =(u16*)  carve((size_t)512*512*2);
  u16*   Wi0a   =(u16*)  carve((size_t)G_*512*2);
  u16*   Whh0b  =(u16*)  carve((size_t)G_*512*2);
  u16*   Wih1b  =(u16*)  carve((size_t)G_*512*2);
  u16*   Whh1b  =(u16*)  carve((size_t)G_*512*2);
  u16*   WoT    =(u16*)  carve((size_t)512*512*2);
  float* lin_enc=(float*)carve((size_t)B_*T_*512*4);
  float* ey_pre =(float*)carve((size_t)B_*U_*G_*4);
  float* hdec   =(float*)carve((size_t)B_*U_*512*4);
  float* lin_dec=(float*)carve((size_t)B_*U_*512*4);
  float* q_g    =(float*)carve(4096*4);
  float* attc   =(float*)carve(4096*4);
  float* states =(float*)carve(6*4096*4);
  float* h0buf=states; float* h1buf=states+2*4096;
  float* c0g=states+4*4096; float* c1g=states+5*4096;

  hipMemsetAsync(states,0,6*4096*4,stream);
  int n1=B_*T_*D_, n2=G_*512;
  k_f2bf    <<<(n1+255)/256,256,0,stream>>>(hs_pad,hs_bf,n1);
  k_trans_bf<<<(512*512+255)/256,256,0,stream>>>(W_att_dec,WdT,512,512);
  k_wi0a    <<<(n2+255)/256,256,0,stream>>>(W_ih0,Wi0a);
  k_f2bf    <<<(n2+255)/256,256,0,stream>>>(W_hh0,Whh0b,n2);
  k_f2bf    <<<(n2+255)/256,256,0,stream>>>(W_ih1,Wih1b,n2);
  k_f2bf    <<<(n2+255)/256,256,0,stream>>>(W_hh1,Whh1b,n2);
  k_woT     <<<(512*512+255)/256,256,0,stream>>>(W_out,WoT);

  // pre GEMMs
  k_gemm<<<dim3(32,8),256,0,stream>>>(hs_pad,nullptr,512, W_att_enc,512,0, b_att_enc,nullptr, 1,1, pe_bf,512, 512);
  k_gemm<<<dim3(32,8),256,0,stream>>>(hs_pad,nullptr,512, W_lin_enc,512,0, b_lin_enc,nullptr, 0,0, lin_enc,512, 512);
  k_gemm<<<dim3(8,32),256,0,stream>>>(emb,ys,512,        W_ih0,1024,1,    b_ih0,b_hh0,      0,0, ey_pre,2048, 512);

  // sequential scan: h0_{u-1} lives in h0buf[u&1]; h1_{v} lives in h1buf[(v+1)&1]
  for(int u=0;u<U_;++u){
    k_q    <<<32,128,0,stream>>>(h0buf+(u&1)*4096, WdT, b_att_dec, q_g);
    k_att  <<<40,256,0,stream>>>(u,q_g,pe_bf,hs_bf,hlens,attc,
              h0buf+(u&1)*4096, h1buf+((u+1)&1)*4096, h1buf+(u&1)*4096,
              Wih1b,Whh1b,b_ih1,b_hh1,c1g,hdec);
    k_lstm0<<<32,256,0,stream>>>(u,attc,h0buf+(u&1)*4096,h0buf+((u+1)&1)*4096,c0g,Wi0a,Whh0b,ey_pre);
  }
  // final LSTM1 for u-1 = 63
  k_att<<<40,256,0,stream>>>(64,q_g,pe_bf,hs_bf,hlens,attc,
          h0buf+0*4096, h1buf+1*4096, h1buf+0*4096,
          Wih1b,Whh1b,b_ih1,b_hh1,c1g,hdec);

  // post GEMM + joint
  k_gemm <<<dim3(8,8),256,0,stream>>>(hdec,nullptr,512, W_lin_dec,512,0, nullptr,nullptr, 0,0, lin_dec,512, 512);
  k_joint<<<2048,256,0,stream>>>(lin_enc,lin_dec,WoT,b_out,out);
}